// Round 7
// baseline (115.859 us; speedup 1.0000x reference)
//
#include <hip/hip_runtime.h>

#define N_NODES 100000
#define N_EDGES 1600000
#define IN_DIM  256
#define OUT_DIM 64

typedef __attribute__((ext_vector_type(8))) short bf16x8;   // 8 bf16 in 4 VGPRs
typedef __attribute__((ext_vector_type(4))) float f32x4;    // MFMA accumulator

// float -> bf16 (round-to-nearest-even)
__device__ __forceinline__ short f2bf(float f) {
    union { float f; unsigned u; } v; v.f = f;
    unsigned r = v.u + 0x7fffu + ((v.u >> 16) & 1u);
    return (short)(r >> 16);
}

// ---------------------------------------------------------------------------
// GEMM via bf16 MFMA: h = x @ w, stored bf16. (~19 us, near its 16 us HBM
// floor: x read 102.4 MB.) Unchanged.
// ---------------------------------------------------------------------------
#define WB_STRIDE 264   // bf16 elems per n-row: 256 + 8 pad

__global__ __launch_bounds__(256)
void gcn_gemm_mfma(const float* __restrict__ x,
                   const float* __restrict__ w,
                   unsigned short* __restrict__ hb)
{
    __shared__ short wb[OUT_DIM * WB_STRIDE];   // 33792 B

    for (int idx = threadIdx.x; idx < IN_DIM * OUT_DIM; idx += 256) {
        int k = idx >> 6;
        int n = idx & 63;
        wb[n * WB_STRIDE + k] = f2bf(w[idx]);
    }
    __syncthreads();

    const int lane = threadIdx.x & 63;
    const int wv   = threadIdx.x >> 6;
    const int r0   = blockIdx.x * 64 + wv * 16;

    const int arow   = r0 + (lane & 15);
    const int arow_c = arow < N_NODES ? arow : N_NODES - 1;
    const int kbase  = (lane >> 4) << 3;                    // 0,8,16,24
    const float* xr  = x + (size_t)arow_c * IN_DIM + kbase;

    const int nlo = lane & 15;
    const short* wb0 = &wb[(0  + nlo) * WB_STRIDE + kbase];
    const short* wb1 = &wb[(16 + nlo) * WB_STRIDE + kbase];
    const short* wb2 = &wb[(32 + nlo) * WB_STRIDE + kbase];
    const short* wb3 = &wb[(48 + nlo) * WB_STRIDE + kbase];

    f32x4 acc0 = {0.f, 0.f, 0.f, 0.f};
    f32x4 acc1 = {0.f, 0.f, 0.f, 0.f};
    f32x4 acc2 = {0.f, 0.f, 0.f, 0.f};
    f32x4 acc3 = {0.f, 0.f, 0.f, 0.f};

#pragma unroll
    for (int k0 = 0; k0 < IN_DIM; k0 += 32) {
        float4 f0 = *(const float4*)(xr + k0);
        float4 f1 = *(const float4*)(xr + k0 + 4);
        bf16x8 a;
        a[0] = f2bf(f0.x); a[1] = f2bf(f0.y); a[2] = f2bf(f0.z); a[3] = f2bf(f0.w);
        a[4] = f2bf(f1.x); a[5] = f2bf(f1.y); a[6] = f2bf(f1.z); a[7] = f2bf(f1.w);

        bf16x8 b0 = *(const bf16x8*)(wb0 + k0);
        bf16x8 b1 = *(const bf16x8*)(wb1 + k0);
        bf16x8 b2 = *(const bf16x8*)(wb2 + k0);
        bf16x8 b3 = *(const bf16x8*)(wb3 + k0);

        acc0 = __builtin_amdgcn_mfma_f32_16x16x32_bf16(a, b0, acc0, 0, 0, 0);
        acc1 = __builtin_amdgcn_mfma_f32_16x16x32_bf16(a, b1, acc1, 0, 0, 0);
        acc2 = __builtin_amdgcn_mfma_f32_16x16x32_bf16(a, b2, acc2, 0, 0, 0);
        acc3 = __builtin_amdgcn_mfma_f32_16x16x32_bf16(a, b3, acc3, 0, 0, 0);
    }

    const int crow0 = r0 + ((lane >> 4) << 2);
#pragma unroll
    for (int rr = 0; rr < 4; ++rr) {
        int row = crow0 + rr;
        if (row < N_NODES) {
            unsigned short* hp = hb + (size_t)row * OUT_DIM + nlo;
            hp[0]  = (unsigned short)f2bf(acc0[rr]);
            hp[16] = (unsigned short)f2bf(acc1[rr]);
            hp[32] = (unsigned short)f2bf(acc2[rr]);
            hp[48] = (unsigned short)f2bf(acc3[rr]);
        }
    }
}

// ---------------------------------------------------------------------------
// Banded SpMM + ReLU.
// R6 post-mortem: three different ILP shapes all ~58-61 us -> memory-side
// (L2-miss queuing on random 128B gathers; h=12.8MB thrashes 4MB/XCD L2).
// Fix: sweep cols in NB=7 bands of 16384 (h-band = 2MB, fits every XCD L2).
// All 1563 blocks co-resident -> whole GPU processes band b together; each
// band fetched ~once per XCD, gathers become L2 hits.
// Per block: bucket edges by (row,band) in LDS (count+scatter, LDS atomics),
// then band-major gather with per-row register accumulators (one drain/row).
// ---------------------------------------------------------------------------
#define SPMM_ROWS_PER_BLOCK 64
#define SEG_CAP 1536       // mean edges/block 1024, sd ~32; fallback beyond
#define BAND_SHIFT 14      // band = col >> 14 ; 16384 rows/band
#define NB 7               // ceil(100000 / 16384)

__device__ __forceinline__ int lower_bound_rows(const int* __restrict__ rows, int val)
{
    int lo = 0, hi = N_EDGES;
    while (lo < hi) {
        int mid = (lo + hi) >> 1;
        if (rows[mid] < val) lo = mid + 1; else hi = mid;
    }
    return lo;
}

__global__ __launch_bounds__(256, 2)
void gcn_spmm_band(const unsigned short* __restrict__ hb,
                   const float* __restrict__ vals,
                   const int* __restrict__ rows,
                   const int* __restrict__ cols,
                   float* __restrict__ out)
{
    __shared__ int   s_starts[SPMM_ROWS_PER_BLOCK + 1];
    __shared__ uint2 s_ec2[SEG_CAP];                        // 12288 B
    __shared__ int   s_cnt [SPMM_ROWS_PER_BLOCK][8];        // 2048 B
    __shared__ int   s_bofs[SPMM_ROWS_PER_BLOCK][8];        // 2048 B
    __shared__ int   s_cur [SPMM_ROWS_PER_BLOCK][8];        // 2048 B

    const int row0 = blockIdx.x * SPMM_ROWS_PER_BLOCK;
    const int t    = threadIdx.x;

    if (t <= SPMM_ROWS_PER_BLOCK) {
        int target = row0 + t;
        s_starts[t] = (target >= N_NODES) ? N_EDGES : lower_bound_rows(rows, target);
    }
    for (int i = t; i < SPMM_ROWS_PER_BLOCK * 8; i += 256) ((int*)s_cnt)[i] = 0;
    __syncthreads();

    const int seg0   = s_starts[0];
    const int segLen = s_starts[SPMM_ROWS_PER_BLOCK] - seg0;
    const bool fits  = (segLen <= SEG_CAP);

    const int lane = t & 63;
    const int wv   = t >> 6;
    const int half = lane >> 5;     // 0: even edges, 1: odd edges of a bucket
    const int sub  = lane & 31;     // dim pair: dims 2*sub, 2*sub+1

    if (fits) {
        // ---- pass A: count edges per (row, band) ----
        for (int i = t; i < segLen; i += 256) {
            int gi = seg0 + i;
            int b  = cols[gi] >> BAND_SHIFT;
            int lo = 0, hi = SPMM_ROWS_PER_BLOCK - 1;       // find row of edge
            while (lo < hi) {
                int mid = (lo + hi + 1) >> 1;
                if (s_starts[mid] <= gi) lo = mid; else hi = mid - 1;
            }
            atomicAdd(&s_cnt[lo][b], 1);
        }
        __syncthreads();
        // ---- per-row exclusive prefix over bands ----
        if (t < SPMM_ROWS_PER_BLOCK) {
            int acc = 0;
#pragma unroll
            for (int b = 0; b < 8; ++b) {
                s_bofs[t][b] = acc;
                s_cur [t][b] = acc;
                acc += s_cnt[t][b];
            }
        }
        __syncthreads();
        // ---- pass B: scatter (val,col) into (row,band)-ordered buckets ----
        for (int i = t; i < segLen; i += 256) {
            int gi = seg0 + i;
            int c  = cols[gi];
            float v = vals[gi];
            int b  = c >> BAND_SHIFT;
            int lo = 0, hi = SPMM_ROWS_PER_BLOCK - 1;
            while (lo < hi) {
                int mid = (lo + hi + 1) >> 1;
                if (s_starts[mid] <= gi) lo = mid; else hi = mid - 1;
            }
            int rbase = s_starts[lo] - seg0;
            int pos   = rbase + atomicAdd(&s_cur[lo][b], 1);
            s_ec2[pos] = make_uint2(__float_as_uint(v), (unsigned)c);
        }
        __syncthreads();

        // ---- band-major gather: 16 rows/wave, accs live across bands ----
        float accL[16], accH[16];
#pragma unroll
        for (int rr = 0; rr < 16; ++rr) { accL[rr] = 0.f; accH[rr] = 0.f; }

        for (int b = 0; b < NB; ++b) {
#pragma unroll
            for (int rr = 0; rr < 16; ++rr) {
                const int r     = wv * 16 + rr;
                const int rbase = s_starts[r] - seg0;
                const int bs    = rbase + s_bofs[r][b];
                const int n     = s_cnt[r][b];
                const int tc    = (n + 1) >> 1;
                for (int i = 0; i < tc; ++i) {
                    int  k  = 2 * i + half;
                    bool ok = k < n;
                    uint2 vc = s_ec2[ok ? (bs + k) : bs];
                    float v  = ok ? __uint_as_float(vc.x) : 0.f;
                    unsigned hx = *(const unsigned*)(hb + (size_t)vc.y * OUT_DIM + 2u * sub);
                    accL[rr] = fmaf(v, __uint_as_float(hx << 16),         accL[rr]);
                    accH[rr] = fmaf(v, __uint_as_float(hx & 0xffff0000u), accH[rr]);
                }
            }
        }

#pragma unroll
        for (int rr = 0; rr < 16; ++rr) {
            int r = row0 + wv * 16 + rr;
            float lo = accL[rr] + __shfl_xor(accL[rr], 32);
            float hi = accH[rr] + __shfl_xor(accH[rr], 32);
            if (half == 0 && r < N_NODES) {
                float2 o;
                o.x = fmaxf(lo, 0.f);
                o.y = fmaxf(hi, 0.f);
                *(float2*)(out + (size_t)r * OUT_DIM + 2u * sub) = o;
            }
        }
    } else {
        // ---- overflow fallback (essentially never): unbanded global loop ----
        for (int rr = wv; rr < SPMM_ROWS_PER_BLOCK; rr += 4) {
            int r = row0 + rr;
            if (r >= N_NODES) break;
            int s = s_starts[rr], e = s_starts[rr + 1];
            int n = e - s, tc = (n + 1) >> 1;
            float aL = 0.f, aH = 0.f;
            for (int i = 0; i < tc; ++i) {
                int ei  = s + 2 * i + half;
                bool ok = ei < e;
                int idx = ok ? ei : s;
                float v = ok ? vals[idx] : 0.f;
                unsigned c  = (unsigned)cols[idx];
                unsigned hx = *(const unsigned*)(hb + (size_t)c * OUT_DIM + 2u * sub);
                aL = fmaf(v, __uint_as_float(hx << 16),         aL);
                aH = fmaf(v, __uint_as_float(hx & 0xffff0000u), aH);
            }
            aL += __shfl_xor(aL, 32);
            aH += __shfl_xor(aH, 32);
            if (half == 0) {
                float2 o;
                o.x = fmaxf(aL, 0.f);
                o.y = fmaxf(aH, 0.f);
                *(float2*)(out + (size_t)r * OUT_DIM + 2u * sub) = o;
            }
        }
    }
}

// ---------------------------------------------------------------------------
extern "C" void kernel_launch(void* const* d_in, const int* in_sizes, int n_in,
                              void* d_out, int out_size, void* d_ws, size_t ws_size,
                              hipStream_t stream)
{
    const float* x    = (const float*)d_in[0];
    const float* w    = (const float*)d_in[1];
    const float* vals = (const float*)d_in[2];
    const int*   rows = (const int*)d_in[3];
    const int*   cols = (const int*)d_in[4];
    float*       out  = (float*)d_out;
    unsigned short* hb = (unsigned short*)d_ws;   // N_NODES*OUT_DIM bf16 = 12.8 MB

    const int gemm_grid = (N_NODES + 63) / 64;
    gcn_gemm_mfma<<<gemm_grid, 256, 0, stream>>>(x, w, hb);

    const int spmm_grid = (N_NODES + SPMM_ROWS_PER_BLOCK - 1) / SPMM_ROWS_PER_BLOCK;
    gcn_spmm_band<<<spmm_grid, 256, 0, stream>>>(hb, vals, rows, cols, out);
}

// Round 8
// 73.392 us; speedup vs baseline: 1.5786x; 1.5786x over previous
//
#include <hip/hip_runtime.h>

#define N_NODES 100000
#define N_EDGES 1600000
#define IN_DIM  256
#define OUT_DIM 64

typedef __attribute__((ext_vector_type(8))) short bf16x8;   // 8 bf16 in 4 VGPRs
typedef __attribute__((ext_vector_type(4))) float f32x4;    // MFMA accumulator

// float -> bf16 (round-to-nearest-even)
__device__ __forceinline__ short f2bf(float f) {
    union { float f; unsigned u; } v; v.f = f;
    unsigned r = v.u + 0x7fffu + ((v.u >> 16) & 1u);
    return (short)(r >> 16);
}

// ---------------------------------------------------------------------------
// GEMM via bf16 MFMA: h = x @ w, stored bf16. (~19 us, at its HBM floor:
// 102.4 MB x read + 12.8 MB h write.) Unchanged.
// ---------------------------------------------------------------------------
#define WB_STRIDE 264   // bf16 elems per n-row: 256 + 8 pad

__global__ __launch_bounds__(256)
void gcn_gemm_mfma(const float* __restrict__ x,
                   const float* __restrict__ w,
                   unsigned short* __restrict__ hb)
{
    __shared__ short wb[OUT_DIM * WB_STRIDE];   // 33792 B

    for (int idx = threadIdx.x; idx < IN_DIM * OUT_DIM; idx += 256) {
        int k = idx >> 6;
        int n = idx & 63;
        wb[n * WB_STRIDE + k] = f2bf(w[idx]);
    }
    __syncthreads();

    const int lane = threadIdx.x & 63;
    const int wv   = threadIdx.x >> 6;
    const int r0   = blockIdx.x * 64 + wv * 16;

    const int arow   = r0 + (lane & 15);
    const int arow_c = arow < N_NODES ? arow : N_NODES - 1;
    const int kbase  = (lane >> 4) << 3;                    // 0,8,16,24
    const float* xr  = x + (size_t)arow_c * IN_DIM + kbase;

    const int nlo = lane & 15;
    const short* wb0 = &wb[(0  + nlo) * WB_STRIDE + kbase];
    const short* wb1 = &wb[(16 + nlo) * WB_STRIDE + kbase];
    const short* wb2 = &wb[(32 + nlo) * WB_STRIDE + kbase];
    const short* wb3 = &wb[(48 + nlo) * WB_STRIDE + kbase];

    f32x4 acc0 = {0.f, 0.f, 0.f, 0.f};
    f32x4 acc1 = {0.f, 0.f, 0.f, 0.f};
    f32x4 acc2 = {0.f, 0.f, 0.f, 0.f};
    f32x4 acc3 = {0.f, 0.f, 0.f, 0.f};

#pragma unroll
    for (int k0 = 0; k0 < IN_DIM; k0 += 32) {
        float4 f0 = *(const float4*)(xr + k0);
        float4 f1 = *(const float4*)(xr + k0 + 4);
        bf16x8 a;
        a[0] = f2bf(f0.x); a[1] = f2bf(f0.y); a[2] = f2bf(f0.z); a[3] = f2bf(f0.w);
        a[4] = f2bf(f1.x); a[5] = f2bf(f1.y); a[6] = f2bf(f1.z); a[7] = f2bf(f1.w);

        bf16x8 b0 = *(const bf16x8*)(wb0 + k0);
        bf16x8 b1 = *(const bf16x8*)(wb1 + k0);
        bf16x8 b2 = *(const bf16x8*)(wb2 + k0);
        bf16x8 b3 = *(const bf16x8*)(wb3 + k0);

        acc0 = __builtin_amdgcn_mfma_f32_16x16x32_bf16(a, b0, acc0, 0, 0, 0);
        acc1 = __builtin_amdgcn_mfma_f32_16x16x32_bf16(a, b1, acc1, 0, 0, 0);
        acc2 = __builtin_amdgcn_mfma_f32_16x16x32_bf16(a, b2, acc2, 0, 0, 0);
        acc3 = __builtin_amdgcn_mfma_f32_16x16x32_bf16(a, b3, acc3, 0, 0, 0);
    }

    const int crow0 = r0 + ((lane >> 4) << 2);
#pragma unroll
    for (int rr = 0; rr < 4; ++rr) {
        int row = crow0 + rr;
        if (row < N_NODES) {
            unsigned short* hp = hb + (size_t)row * OUT_DIM + nlo;
            hp[0]  = (unsigned short)f2bf(acc0[rr]);
            hp[16] = (unsigned short)f2bf(acc1[rr]);
            hp[32] = (unsigned short)f2bf(acc2[rr]);
            hp[48] = (unsigned short)f2bf(acc3[rr]);
        }
    }
}

// ---------------------------------------------------------------------------
// One-time CSR boundary build: row_starts[r] = lower_bound(rows, r) for
// r in [0, N_NODES]. Fully parallel (one thread per boundary); rows[] is
// 6.4 MB -> L2-resident during the 21-step searches. Replaces 3125 x 33
// serial per-block searches (2.2M chained random loads) in the SpMM.
// ---------------------------------------------------------------------------
__global__ __launch_bounds__(256)
void build_row_starts(const int* __restrict__ rows, int* __restrict__ starts)
{
    int r = blockIdx.x * 256 + threadIdx.x;
    if (r > N_NODES) return;
    int lo = 0, hi = N_EDGES;
    while (lo < hi) {
        int mid = (lo + hi) >> 1;
        if (rows[mid] < r) lo = mid + 1; else hi = mid;
    }
    starts[r] = lo;
}

// ---------------------------------------------------------------------------
// SpMM + ReLU (R6 structure, equal-best 57.8 us, minus the serial binary-
// search prologue). Half-wave pairing: lanes 0-31 even edges, 32-63 odd;
// each lane reads a uint (2 bf16 dims) -> one load covers 2 edge rows.
// 8-deep explicit load batches. (vals,cols) staged interleaved in LDS.
// ---------------------------------------------------------------------------
#define SPMM_ROWS_PER_BLOCK 32
#define SEG_CAP 1024   // mean edges/block = 512, sd ~23; fallback if exceeded

__global__ __launch_bounds__(256, 2)
void gcn_spmm_relu_kernel(const unsigned short* __restrict__ hb,
                          const float* __restrict__ vals,
                          const int* __restrict__ row_starts,
                          const int* __restrict__ cols,
                          float* __restrict__ out)
{
    __shared__ int   starts[SPMM_ROWS_PER_BLOCK + 1];
    __shared__ uint2 s_ec[SEG_CAP];   // .x = val bits, .y = col

    const int row0 = blockIdx.x * SPMM_ROWS_PER_BLOCK;
    const int t    = threadIdx.x;

    if (t <= SPMM_ROWS_PER_BLOCK) {
        starts[t] = row_starts[row0 + t];     // coalesced; replaces 21-step search
    }
    __syncthreads();

    const int seg0   = starts[0];
    const int segLen = starts[SPMM_ROWS_PER_BLOCK] - seg0;
    const bool fits  = (segLen <= SEG_CAP);

    if (fits) {
        for (int i = t; i < segLen; i += 256) {
            s_ec[i] = make_uint2(__float_as_uint(vals[seg0 + i]),
                                 (unsigned)cols[seg0 + i]);
        }
    }
    __syncthreads();

    const int lane = t & 63;
    const int wv   = t >> 6;
    const int half = lane >> 5;       // 0: even edges, 1: odd edges
    const int sub  = lane & 31;       // dim pair index: dims 2*sub, 2*sub+1

    for (int rr = wv; rr < SPMM_ROWS_PER_BLOCK; rr += 4) {
        const int r = row0 + rr;                   // N_NODES % 32 == 0, no tail
        const int s = starts[rr]     - seg0;
        const int e = starts[rr + 1] - seg0;
        const int tc = (e - s + 1) >> 1;           // paired iterations

        float aL[4] = {0.f, 0.f, 0.f, 0.f};
        float aH[4] = {0.f, 0.f, 0.f, 0.f};

        if (fits) {
            int i = 0;
            // ---- 8-deep batch: 8 gathers in flight before first consume ----
            for (; i + 8 <= tc; i += 8) {
                float    vv[8];
                unsigned hx[8];
#pragma unroll
                for (int g = 0; g < 8; ++g) {
                    int ei   = s + 2 * (i + g) + half;
                    bool ok  = ei < e;
                    uint2 vc = s_ec[ok ? ei : (e - 1)];
                    vv[g] = ok ? __uint_as_float(vc.x) : 0.f;
                    hx[g] = *(const unsigned*)(hb + (size_t)vc.y * OUT_DIM + 2u * sub);
                }
#pragma unroll
                for (int g = 0; g < 8; ++g) {
                    aL[g & 3] = fmaf(vv[g], __uint_as_float(hx[g] << 16),         aL[g & 3]);
                    aH[g & 3] = fmaf(vv[g], __uint_as_float(hx[g] & 0xffff0000u), aH[g & 3]);
                }
            }
            // ---- 4-deep batch ----
            if (i + 4 <= tc) {
                float    vv[4];
                unsigned hx[4];
#pragma unroll
                for (int g = 0; g < 4; ++g) {
                    int ei   = s + 2 * (i + g) + half;
                    bool ok  = ei < e;
                    uint2 vc = s_ec[ok ? ei : (e - 1)];
                    vv[g] = ok ? __uint_as_float(vc.x) : 0.f;
                    hx[g] = *(const unsigned*)(hb + (size_t)vc.y * OUT_DIM + 2u * sub);
                }
#pragma unroll
                for (int g = 0; g < 4; ++g) {
                    aL[g] = fmaf(vv[g], __uint_as_float(hx[g] << 16),         aL[g]);
                    aH[g] = fmaf(vv[g], __uint_as_float(hx[g] & 0xffff0000u), aH[g]);
                }
                i += 4;
            }
            // ---- scalar tail ----
            for (; i < tc; ++i) {
                int ei   = s + 2 * i + half;
                bool ok  = ei < e;
                uint2 vc = s_ec[ok ? ei : (e - 1)];
                float v  = ok ? __uint_as_float(vc.x) : 0.f;
                unsigned hx = *(const unsigned*)(hb + (size_t)vc.y * OUT_DIM + 2u * sub);
                aL[0] = fmaf(v, __uint_as_float(hx << 16),         aL[0]);
                aH[0] = fmaf(v, __uint_as_float(hx & 0xffff0000u), aH[0]);
            }
        } else {
            // overflow fallback (essentially never): global reads, same pairing
            for (int i = 0; i < tc; ++i) {
                int ei   = s + 2 * i + half;
                bool ok  = ei < e;
                int eidx = (ok ? ei : e - 1) + seg0;
                float v  = ok ? vals[eidx] : 0.f;
                unsigned c = (unsigned)cols[eidx];
                unsigned hx = *(const unsigned*)(hb + (size_t)c * OUT_DIM + 2u * sub);
                aL[0] = fmaf(v, __uint_as_float(hx << 16),         aL[0]);
                aH[0] = fmaf(v, __uint_as_float(hx & 0xffff0000u), aH[0]);
            }
        }

        float lo = (aL[0] + aL[1]) + (aL[2] + aL[3]);
        float hi = (aH[0] + aH[1]) + (aH[2] + aH[3]);
        lo += __shfl_xor(lo, 32);
        hi += __shfl_xor(hi, 32);

        if (half == 0) {
            float2 o;
            o.x = fmaxf(lo, 0.f);
            o.y = fmaxf(hi, 0.f);
            *(float2*)(out + (size_t)r * OUT_DIM + 2u * sub) = o;   // 256B/half-wave
        }
    }
}

// ---------------------------------------------------------------------------
extern "C" void kernel_launch(void* const* d_in, const int* in_sizes, int n_in,
                              void* d_out, int out_size, void* d_ws, size_t ws_size,
                              hipStream_t stream)
{
    const float* x    = (const float*)d_in[0];
    const float* w    = (const float*)d_in[1];
    const float* vals = (const float*)d_in[2];
    const int*   rows = (const int*)d_in[3];
    const int*   cols = (const int*)d_in[4];
    float*       out  = (float*)d_out;

    // workspace layout: [ hb: 12.8 MB bf16 ][ row_starts: 100001 ints ]
    unsigned short* hb = (unsigned short*)d_ws;
    int* row_starts = (int*)((char*)d_ws + (size_t)N_NODES * OUT_DIM * sizeof(unsigned short));

    build_row_starts<<<(N_NODES + 1 + 255) / 256, 256, 0, stream>>>(rows, row_starts);

    const int gemm_grid = (N_NODES + 63) / 64;
    gcn_gemm_mfma<<<gemm_grid, 256, 0, stream>>>(x, w, hb);

    const int spmm_grid = (N_NODES + SPMM_ROWS_PER_BLOCK - 1) / SPMM_ROWS_PER_BLOCK;
    gcn_spmm_relu_kernel<<<spmm_grid, 256, 0, stream>>>(hb, vals, row_starts, cols, out);
}